// Round 1
// baseline (2347.461 us; speedup 1.0000x reference)
//
#include <hip/hip_runtime.h>

// Seq2Seq LSTM (B=1024, T_IN=168, F_IN=8, H=256, T_OUT=96) on gfx950.
// Strategy: batch-parallel persistent blocks. 64 blocks x 512 threads (8 waves).
// Each block owns 16 batch rows for the WHOLE 264-step recurrence (no grid sync).
// Each wave owns hidden slice [wv*32, wv*32+32) -> computes gate columns
// {j, 256+j, 512+j, 768+j}: activations + c-state are lane-local.
// f16 MFMA (16x16x32), fp32 accumulate + fp32 c/h state; h stored f16 in
// ping-pong LDS. Weights pre-packed fragment-linear (coalesced dwordx4 loads),
// streamed from L2 each step with distance-2 prefetch.
// K padded to 288 = 256 (h) + 32 (x features / pred + zero pad), so the input
// projection folds into the same GEMM (weight rows for pad-k are packed as 0).

typedef _Float16 f16x8 __attribute__((ext_vector_type(8)));
typedef float f32x4 __attribute__((ext_vector_type(4)));

#define ROWP 296            // LDS A row stride in f16 (288 + 8 pad; 592B = 16B-aligned, bank-spread)
#define WPW  36864          // packed f16 per wave per weight set: 9kt * 8nt * 64lane * 8
#define NSTEPS_ENC 168
#define NSTEPS_DEC 96

__device__ __forceinline__ float sigm(float x) {
    float e = __builtin_amdgcn_exp2f(-1.4426950408889634f * x);
    return __builtin_amdgcn_rcpf(1.0f + e);
}
__device__ __forceinline__ float tanh_f(float x) {
    float e = __builtin_amdgcn_exp2f(-2.8853900817779268f * x);
    return 2.0f * __builtin_amdgcn_rcpf(1.0f + e) - 1.0f;
}

__device__ __forceinline__ void loadB(f16x8 b[8], const _Float16* __restrict__ wp, int kt, int lane) {
#pragma unroll
    for (int nt = 0; nt < 8; ++nt)
        b[nt] = *(const f16x8*)(wp + ((kt * 8 + nt) * 64 + lane) * 8);
}

__device__ __forceinline__ void mfma8(f32x4 acc[8], f16x8 a, const f16x8 b[8]) {
#pragma unroll
    for (int nt = 0; nt < 8; ++nt)
        acc[nt] = __builtin_amdgcn_mfma_f32_16x16x32_f16(a, b[nt], acc[nt], 0, 0, 0);
}

// gates GEMM: acc[nt] (16 batch rows x 16 gate cols each) += A(16x288) * W^T
__device__ __forceinline__ void gemm_step(f32x4 acc[8], const _Float16 (*Ar)[ROWP],
                                          const _Float16* __restrict__ wp,
                                          int lane, int l15, int lg) {
    f16x8 b0[8], b1[8], b2[8];
    loadB(b0, wp, 0, lane);
    loadB(b1, wp, 1, lane);
    f16x8 af[9];
#pragma unroll
    for (int kt = 0; kt < 9; ++kt)
        af[kt] = *(const f16x8*)&Ar[l15][kt * 32 + lg * 8];
    loadB(b2, wp, 2, lane); mfma8(acc, af[0], b0);
    loadB(b0, wp, 3, lane); mfma8(acc, af[1], b1);
    loadB(b1, wp, 4, lane); mfma8(acc, af[2], b2);
    loadB(b2, wp, 5, lane); mfma8(acc, af[3], b0);
    loadB(b0, wp, 6, lane); mfma8(acc, af[4], b1);
    loadB(b1, wp, 7, lane); mfma8(acc, af[5], b2);
    loadB(b2, wp, 8, lane); mfma8(acc, af[6], b0);
    mfma8(acc, af[7], b1);
    mfma8(acc, af[8], b2);
}

// ---------- setup kernels ----------

// inputs (B,T,F) f32 -> xf16 [t][b][f] f16
__global__ void k_convert_x(const float* __restrict__ in, _Float16* __restrict__ xf16) {
    int idx = blockIdx.x * 256 + threadIdx.x;     // (t*1024 + b)*8 + f
    if (idx >= 168 * 1024 * 8) return;
    int f = idx & 7;
    int b = (idx >> 3) & 1023;
    int t = idx >> 13;
    xf16[idx] = (_Float16)in[(b * 168 + t) * 8 + f];
}

// pack weights into fragment-linear layout:
// flat = (((wv*9 + kt)*8 + nt)*64 + lane)*8 + j
// n = gt*256 + wv*32 + half*16 + (lane&15), nt = gt*2 + half
// k = kt*32 + (lane>>4)*8 + j ; k<256 -> Whh[n][k]; k-256<IN -> Wih[n][k-256]; else 0
__global__ void k_pack_w(const float* __restrict__ Whh, const float* __restrict__ Wih,
                         int IN, _Float16* __restrict__ Wp) {
    int idx = blockIdx.x * 256 + threadIdx.x;
    if (idx >= 294912) return;
    int j    = idx & 7;
    int lane = (idx >> 3) & 63;
    int nt   = (idx >> 9) & 7;
    int kt   = (idx >> 12) % 9;
    int wv   = idx / 36864;
    int n = (nt >> 1) * 256 + wv * 32 + (nt & 1) * 16 + (lane & 15);
    int k = kt * 32 + (lane >> 4) * 8 + j;
    float v = 0.0f;
    if (k < 256)            v = Whh[n * 256 + k];
    else if (k - 256 < IN)  v = Wih[n * IN + (k - 256)];
    Wp[idx] = (_Float16)v;
}

__global__ void k_bias(const float* __restrict__ bih_e, const float* __restrict__ bhh_e,
                       const float* __restrict__ bih_d, const float* __restrict__ bhh_d,
                       float* __restrict__ bE, float* __restrict__ bD) {
    int n = blockIdx.x * 256 + threadIdx.x;
    if (n < 1024) {
        bE[n] = bih_e[n] + bhh_e[n];
        bD[n] = bih_d[n] + bhh_d[n];
    }
}

// ---------- main persistent kernel ----------

__global__ __launch_bounds__(512, 2) void lstm_seq2seq(
    const _Float16* __restrict__ xf16,
    const _Float16* __restrict__ WpE,
    const _Float16* __restrict__ WpD,
    const float* __restrict__ biasE,
    const float* __restrict__ biasD,
    const float* __restrict__ fcW,
    const float* __restrict__ fcb,
    float* __restrict__ out) {

    __shared__ _Float16 A[2][16][ROWP];   // ping-pong [h(256) | x(32 incl pad)] per batch row
    __shared__ float partial[8][16];      // decoder fc partials per wave
    __shared__ float outstage[16][96];    // staged predictions

    const int tid = threadIdx.x;
    const int lane = tid & 63;
    const int wv  = tid >> 6;
    const int l15 = lane & 15;
    const int lg  = lane >> 4;
    const int b0  = blockIdx.x * 16;

    // zero both A buffers (pad cols must be 0 forever; MFMA reads them)
    for (int i = tid; i < 2 * 16 * ROWP; i += 512)
        (&A[0][0][0])[i] = (_Float16)0.0f;

    float bE[8];
#pragma unroll
    for (int nt = 0; nt < 8; ++nt) {
        int n = (nt >> 1) * 256 + wv * 32 + (nt & 1) * 16 + l15;
        bE[nt] = biasE[n];
    }
    float c_st[2][4] = {{0.f,0.f,0.f,0.f},{0.f,0.f,0.f,0.f}};
    const _Float16* wpe = WpE + wv * WPW;
    const _Float16* wpd = WpD + wv * WPW;

    __syncthreads();
    // x_0 into A[0]
    if (tid < 128) {
        int m = tid >> 3, f = tid & 7;
        A[0][m][256 + f] = xf16[(size_t)(b0 + m) * 8 + f];   // t = 0
    }
    __syncthreads();

    // ===================== encoder: 168 steps =====================
    for (int t = 0; t < NSTEPS_ENC; ++t) {
        const int R = t & 1, Wb = R ^ 1;
        f32x4 acc[8];
#pragma unroll
        for (int nt = 0; nt < 8; ++nt) { f32x4 v = {bE[nt], bE[nt], bE[nt], bE[nt]}; acc[nt] = v; }
        gemm_step(acc, A[R], wpe, lane, l15, lg);

#pragma unroll
        for (int half = 0; half < 2; ++half) {
#pragma unroll
            for (int r = 0; r < 4; ++r) {
                float iv = acc[0 + half][r];
                float fv = acc[2 + half][r];
                float gv = acc[4 + half][r];
                float ov = acc[6 + half][r];
                float cn = sigm(fv) * c_st[half][r] + sigm(iv) * tanh_f(gv);
                c_st[half][r] = cn;
                float hn = sigm(ov) * tanh_f(cn);
                A[Wb][lg * 4 + r][wv * 32 + half * 16 + l15] = (_Float16)hn;
            }
        }
        if (t < NSTEPS_ENC - 1) {
            if (tid < 128) {
                int m = tid >> 3, f = tid & 7;
                A[Wb][m][256 + f] = xf16[(size_t)((t + 1) * 1024 + b0 + m) * 8 + f];
            }
        } else {
            // decoder x0 = inputs[:, -1, 0]; zero remaining x features
            if (tid < 16) {
                A[Wb][tid][256] = xf16[(size_t)(167 * 1024 + b0 + tid) * 8 + 0];
#pragma unroll
                for (int f = 1; f < 8; ++f) A[Wb][tid][256 + f] = (_Float16)0.0f;
            }
        }
        __syncthreads();
    }

    // decoder constants (loaded after encoder to limit live ranges)
    float bD[8];
#pragma unroll
    for (int nt = 0; nt < 8; ++nt) {
        int n = (nt >> 1) * 256 + wv * 32 + (nt & 1) * 16 + l15;
        bD[nt] = biasD[n];
    }
    float fcw0 = fcW[wv * 32 + l15];
    float fcw1 = fcW[wv * 32 + 16 + l15];
    float fcbv = fcb[0];

    // ===================== decoder: 96 steps (autoregressive) =====================
    for (int s = 0; s < NSTEPS_DEC; ++s) {
        const int R = s & 1, Wb = R ^ 1;   // continues encoder parity (168 is even)
        f32x4 acc[8];
#pragma unroll
        for (int nt = 0; nt < 8; ++nt) { f32x4 v = {bD[nt], bD[nt], bD[nt], bD[nt]}; acc[nt] = v; }
        gemm_step(acc, A[R], wpd, lane, l15, lg);

        float hnv[2][4];
#pragma unroll
        for (int half = 0; half < 2; ++half) {
#pragma unroll
            for (int r = 0; r < 4; ++r) {
                float iv = acc[0 + half][r];
                float fv = acc[2 + half][r];
                float gv = acc[4 + half][r];
                float ov = acc[6 + half][r];
                float cn = sigm(fv) * c_st[half][r] + sigm(iv) * tanh_f(gv);
                c_st[half][r] = cn;
                float hn = sigm(ov) * tanh_f(cn);
                hnv[half][r] = hn;
                A[Wb][lg * 4 + r][wv * 32 + half * 16 + l15] = (_Float16)hn;
            }
        }
        // fc dot: reduce over this wave's 32 hidden cols (16-lane shfl groups)
#pragma unroll
        for (int r = 0; r < 4; ++r) {
            float pv = hnv[0][r] * fcw0 + hnv[1][r] * fcw1;
            pv += __shfl_xor(pv, 1);
            pv += __shfl_xor(pv, 2);
            pv += __shfl_xor(pv, 4);
            pv += __shfl_xor(pv, 8);
            if (l15 == 0) partial[wv][lg * 4 + r] = pv;
        }
        __syncthreads();
        if (tid < 16) {
            float pr = fcbv;
#pragma unroll
            for (int w = 0; w < 8; ++w) pr += partial[w][tid];
            outstage[tid][s] = pr;
            A[Wb][tid][256] = (_Float16)pr;   // feed prediction back as next x
        }
        __syncthreads();
    }

    // dump staged predictions: out[(b0+m)*96 + t]
    for (int i = tid; i < 16 * 96; i += 512) {
        int m = i / 96, tt = i - m * 96;
        out[(size_t)(b0 + m) * 96 + tt] = outstage[m][tt];
    }
}

// ---------- launch ----------

extern "C" void kernel_launch(void* const* d_in, const int* in_sizes, int n_in,
                              void* d_out, int out_size, void* d_ws, size_t ws_size,
                              hipStream_t stream) {
    const float* inputs  = (const float*)d_in[0];
    const float* enc_Wih = (const float*)d_in[1];
    const float* enc_Whh = (const float*)d_in[2];
    const float* enc_bih = (const float*)d_in[3];
    const float* enc_bhh = (const float*)d_in[4];
    const float* dec_Wih = (const float*)d_in[5];
    const float* dec_Whh = (const float*)d_in[6];
    const float* dec_bih = (const float*)d_in[7];
    const float* dec_bhh = (const float*)d_in[8];
    const float* fc_W    = (const float*)d_in[9];
    const float* fc_b    = (const float*)d_in[10];

    char* ws = (char*)d_ws;
    _Float16* xf16 = (_Float16*)(ws);                       // 168*1024*8*2   = 2,752,512 B
    _Float16* WpE  = (_Float16*)(ws + 2752512);             // 294912*2       =   589,824 B
    _Float16* WpD  = (_Float16*)(ws + 2752512 + 589824);    //                =   589,824 B
    float*    bE   = (float*)(ws + 3932160);                // 4 KB
    float*    bD   = (float*)(ws + 3936256);                // 4 KB

    k_convert_x<<<dim3(5376), dim3(256), 0, stream>>>(inputs, xf16);
    k_pack_w<<<dim3(1152), dim3(256), 0, stream>>>(enc_Whh, enc_Wih, 8, WpE);
    k_pack_w<<<dim3(1152), dim3(256), 0, stream>>>(dec_Whh, dec_Wih, 1, WpD);
    k_bias<<<dim3(4), dim3(256), 0, stream>>>(enc_bih, enc_bhh, dec_bih, dec_bhh, bE, bD);

    lstm_seq2seq<<<dim3(64), dim3(512), 0, stream>>>(xf16, WpE, WpD, bE, bD, fc_W, fc_b, (float*)d_out);
}

// Round 2
// 1212.965 us; speedup vs baseline: 1.9353x; 1.9353x over previous
//
#include <hip/hip_runtime.h>

// Seq2Seq LSTM (B=1024, T_IN=168, F_IN=8, H=256, T_OUT=96) on gfx950.
// Round 2: weight-resident design. The round-1 kernel was per-CU VMEM-BW bound
// (576 KB of weights re-read per CU per step through a ~64 B/cyc L1/TA path =
// ~9.2k cyc/step floor; measured 21k). Now weights live on-chip:
//   kt 0..4  -> VGPR-resident (40 f16x8 frags = 160 VGPRs per wave)
//   kt 5..6  -> LDS-resident  (128 KB per CU)
//   kt 7..8  -> streamed from L2 each step (128 KB/CU/step, 2 batches of 8)
// 64 blocks x 512 threads, 16 batch rows per block, MFMA f32_16x16x32_f16,
// fp32 state. Same packing/layout as round 1.

typedef _Float16 f16x8 __attribute__((ext_vector_type(8)));
typedef float f32x4 __attribute__((ext_vector_type(4)));

#define ROWP 296            // LDS A row stride in f16
#define WPW  36864          // packed f16 per wave per weight set: 9kt * 8nt * 64lane * 8
#define NSTEPS_ENC 168
#define NSTEPS_DEC 96

__device__ __forceinline__ float sigm(float x) {
    float e = __builtin_amdgcn_exp2f(-1.4426950408889634f * x);
    return __builtin_amdgcn_rcpf(1.0f + e);
}
__device__ __forceinline__ float tanh_f(float x) {
    float e = __builtin_amdgcn_exp2f(-2.8853900817779268f * x);
    return 2.0f * __builtin_amdgcn_rcpf(1.0f + e) - 1.0f;
}

// one recurrence-step GEMM: acc[nt] += A(16x288) * W^T slice
// wr: reg-resident kt0..4; Bw: LDS-resident kt5..6; wp: streamed kt7..8
__device__ __forceinline__ void step_gemm(f32x4 acc[8],
                                          const f16x8 wr[5][8],
                                          const f16x8 (*Bw)[64],
                                          const _Float16* __restrict__ wp,
                                          const _Float16 (*Ar)[ROWP],
                                          int lane, int l15, int lg) {
    // stream batch 1 (kt=7) — issue first so latency hides under resident MFMAs
    f16x8 s7[8];
#pragma unroll
    for (int nt = 0; nt < 8; ++nt)
        s7[nt] = *(const f16x8*)(wp + ((7 * 8 + nt) * 64 + lane) * 8);

    // register-resident kt 0..4
#pragma unroll
    for (int kt = 0; kt < 5; ++kt) {
        f16x8 a = *(const f16x8*)&Ar[l15][kt * 32 + lg * 8];
#pragma unroll
        for (int nt = 0; nt < 8; ++nt)
            acc[nt] = __builtin_amdgcn_mfma_f32_16x16x32_f16(a, wr[kt][nt], acc[nt], 0, 0, 0);
    }
    // consume stream batch 1
    {
        f16x8 a = *(const f16x8*)&Ar[l15][7 * 32 + lg * 8];
#pragma unroll
        for (int nt = 0; nt < 8; ++nt)
            acc[nt] = __builtin_amdgcn_mfma_f32_16x16x32_f16(a, s7[nt], acc[nt], 0, 0, 0);
    }
    // keep batch-2 loads from being hoisted above batch-1 consumption (VGPR cap)
    __builtin_amdgcn_sched_barrier(0);
    // stream batch 2 (kt=8)
    f16x8 s8[8];
#pragma unroll
    for (int nt = 0; nt < 8; ++nt)
        s8[nt] = *(const f16x8*)(wp + ((8 * 8 + nt) * 64 + lane) * 8);
    // LDS-resident kt 5..6 (ds_reads cover batch-2 latency)
#pragma unroll
    for (int kt = 5; kt < 7; ++kt) {
        f16x8 a = *(const f16x8*)&Ar[l15][kt * 32 + lg * 8];
#pragma unroll
        for (int nt = 0; nt < 8; ++nt) {
            f16x8 b = Bw[(kt - 5) * 8 + nt][lane];
            acc[nt] = __builtin_amdgcn_mfma_f32_16x16x32_f16(a, b, acc[nt], 0, 0, 0);
        }
    }
    // consume stream batch 2
    {
        f16x8 a = *(const f16x8*)&Ar[l15][8 * 32 + lg * 8];
#pragma unroll
        for (int nt = 0; nt < 8; ++nt)
            acc[nt] = __builtin_amdgcn_mfma_f32_16x16x32_f16(a, s8[nt], acc[nt], 0, 0, 0);
    }
}

// load one phase's weights: regs (kt0..4), LDS (kt5..6), bias -> LDS
__device__ __forceinline__ void load_phase(f16x8 wr[5][8], f16x8 (*Bw)[64],
                                           const _Float16* __restrict__ wp,
                                           float* __restrict__ bL,
                                           const float* __restrict__ bias,
                                           int lane, int wv, int l15) {
#pragma unroll
    for (int kt = 0; kt < 5; ++kt)
#pragma unroll
        for (int nt = 0; nt < 8; ++nt)
            wr[kt][nt] = *(const f16x8*)(wp + ((kt * 8 + nt) * 64 + lane) * 8);
#pragma unroll
    for (int kt = 5; kt < 7; ++kt)
#pragma unroll
        for (int nt = 0; nt < 8; ++nt)
            Bw[(kt - 5) * 8 + nt][lane] = *(const f16x8*)(wp + ((kt * 8 + nt) * 64 + lane) * 8);
    if (lane < 16) {
#pragma unroll
        for (int nt = 0; nt < 8; ++nt)
            bL[wv * 128 + l15 * 8 + nt] = bias[(nt >> 1) * 256 + wv * 32 + (nt & 1) * 16 + l15];
    }
}

// ---------- setup kernels (unchanged from round 1) ----------

__global__ void k_convert_x(const float* __restrict__ in, _Float16* __restrict__ xf16) {
    int idx = blockIdx.x * 256 + threadIdx.x;
    if (idx >= 168 * 1024 * 8) return;
    int f = idx & 7;
    int b = (idx >> 3) & 1023;
    int t = idx >> 13;
    xf16[idx] = (_Float16)in[(b * 168 + t) * 8 + f];
}

__global__ void k_pack_w(const float* __restrict__ Whh, const float* __restrict__ Wih,
                         int IN, _Float16* __restrict__ Wp) {
    int idx = blockIdx.x * 256 + threadIdx.x;
    if (idx >= 294912) return;
    int j    = idx & 7;
    int lane = (idx >> 3) & 63;
    int nt   = (idx >> 9) & 7;
    int kt   = (idx >> 12) % 9;
    int wv   = idx / 36864;
    int n = (nt >> 1) * 256 + wv * 32 + (nt & 1) * 16 + (lane & 15);
    int k = kt * 32 + (lane >> 4) * 8 + j;
    float v = 0.0f;
    if (k < 256)            v = Whh[n * 256 + k];
    else if (k - 256 < IN)  v = Wih[n * IN + (k - 256)];
    Wp[idx] = (_Float16)v;
}

// ---------- main persistent kernel ----------

__global__ __launch_bounds__(512, 2) void lstm_seq2seq(
    const _Float16* __restrict__ xf16,
    const _Float16* __restrict__ WpE,
    const _Float16* __restrict__ WpD,
    const float* __restrict__ bihE, const float* __restrict__ bhhE,
    const float* __restrict__ bihD, const float* __restrict__ bhhD,
    const float* __restrict__ fcW,
    const float* __restrict__ fcb,
    float* __restrict__ out) {

    __shared__ f16x8 Blds[8][16][64];      // 128 KB: LDS-resident weight frags
    __shared__ _Float16 A[2][16][ROWP];    // 18.9 KB: ping-pong [h | x] per batch row
    __shared__ float partial[8][16];       // decoder fc partials
    __shared__ float bL[8 * 128];          // 4 KB: per-wave bias (current phase)

    const int tid = threadIdx.x;
    const int lane = tid & 63;
    const int wv  = tid >> 6;
    const int l15 = lane & 15;
    const int lg  = lane >> 4;
    const int b0  = blockIdx.x * 16;

    // zero A (pad cols must stay 0; h cols = h0 = 0)
    for (int i = tid; i < 2 * 16 * ROWP; i += 512)
        (&A[0][0][0])[i] = (_Float16)0.0f;

    f16x8 wr[5][8];
    const _Float16* wpe = WpE + wv * WPW;
    const _Float16* wpd = WpD + wv * WPW;

    // encoder bias = bih + bhh (combined on the fly into bL)
    if (lane < 16) {
#pragma unroll
        for (int nt = 0; nt < 8; ++nt) {
            int n = (nt >> 1) * 256 + wv * 32 + (nt & 1) * 16 + l15;
            bL[wv * 128 + l15 * 8 + nt] = bihE[n] + bhhE[n];
        }
    }
#pragma unroll
    for (int kt = 0; kt < 5; ++kt)
#pragma unroll
        for (int nt = 0; nt < 8; ++nt)
            wr[kt][nt] = *(const f16x8*)(wpe + ((kt * 8 + nt) * 64 + lane) * 8);
#pragma unroll
    for (int kt = 5; kt < 7; ++kt)
#pragma unroll
        for (int nt = 0; nt < 8; ++nt)
            Blds[wv][(kt - 5) * 8 + nt][lane] = *(const f16x8*)(wpe + ((kt * 8 + nt) * 64 + lane) * 8);

    float c_st[2][4] = {{0.f,0.f,0.f,0.f},{0.f,0.f,0.f,0.f}};

    __syncthreads();
    if (tid < 128) {                       // x_0 into A[0]
        int m = tid >> 3, f = tid & 7;
        A[0][m][256 + f] = xf16[(size_t)(b0 + m) * 8 + f];
    }
    __syncthreads();

    // ===================== encoder: 168 steps =====================
#pragma unroll 1
    for (int t = 0; t < NSTEPS_ENC; ++t) {
        const int R = t & 1, Wb = R ^ 1;
        f32x4 bb0 = *(const f32x4*)&bL[wv * 128 + l15 * 8];
        f32x4 bb1 = *(const f32x4*)&bL[wv * 128 + l15 * 8 + 4];
        f32x4 acc[8];
#pragma unroll
        for (int nt = 0; nt < 8; ++nt) {
            float b = (nt < 4) ? bb0[nt & 3] : bb1[nt & 3];
            f32x4 v = {b, b, b, b};
            acc[nt] = v;
        }
        step_gemm(acc, wr, Blds[wv], wpe, A[R], lane, l15, lg);

#pragma unroll
        for (int half = 0; half < 2; ++half) {
#pragma unroll
            for (int r = 0; r < 4; ++r) {
                float iv = acc[0 + half][r];
                float fv = acc[2 + half][r];
                float gv = acc[4 + half][r];
                float ov = acc[6 + half][r];
                float cn = sigm(fv) * c_st[half][r] + sigm(iv) * tanh_f(gv);
                c_st[half][r] = cn;
                float hn = sigm(ov) * tanh_f(cn);
                A[Wb][lg * 4 + r][wv * 32 + half * 16 + l15] = (_Float16)hn;
            }
        }
        if (t < NSTEPS_ENC - 1) {
            if (tid < 128) {
                int m = tid >> 3, f = tid & 7;
                A[Wb][m][256 + f] = xf16[(size_t)((t + 1) * 1024 + b0 + m) * 8 + f];
            }
        } else {
            if (tid < 16) {
                A[Wb][tid][256] = xf16[(size_t)(167 * 1024 + b0 + tid) * 8 + 0];
#pragma unroll
                for (int f = 1; f < 8; ++f) A[Wb][tid][256 + f] = (_Float16)0.0f;
            }
        }
        __syncthreads();
    }

    // ---------- phase switch: reload weights/bias for decoder ----------
    if (lane < 16) {
#pragma unroll
        for (int nt = 0; nt < 8; ++nt) {
            int n = (nt >> 1) * 256 + wv * 32 + (nt & 1) * 16 + l15;
            bL[wv * 128 + l15 * 8 + nt] = bihD[n] + bhhD[n];
        }
    }
#pragma unroll
    for (int kt = 0; kt < 5; ++kt)
#pragma unroll
        for (int nt = 0; nt < 8; ++nt)
            wr[kt][nt] = *(const f16x8*)(wpd + ((kt * 8 + nt) * 64 + lane) * 8);
#pragma unroll
    for (int kt = 5; kt < 7; ++kt)
#pragma unroll
        for (int nt = 0; nt < 8; ++nt)
            Blds[wv][(kt - 5) * 8 + nt][lane] = *(const f16x8*)(wpd + ((kt * 8 + nt) * 64 + lane) * 8);
    float fcw0 = fcW[wv * 32 + l15];
    float fcw1 = fcW[wv * 32 + 16 + l15];
    float fcbv = fcb[0];
    __syncthreads();

    // ===================== decoder: 96 steps (autoregressive) =====================
#pragma unroll 1
    for (int s = 0; s < NSTEPS_DEC; ++s) {
        const int R = s & 1, Wb = R ^ 1;   // continues encoder parity (168 even)
        f32x4 bb0 = *(const f32x4*)&bL[wv * 128 + l15 * 8];
        f32x4 bb1 = *(const f32x4*)&bL[wv * 128 + l15 * 8 + 4];
        f32x4 acc[8];
#pragma unroll
        for (int nt = 0; nt < 8; ++nt) {
            float b = (nt < 4) ? bb0[nt & 3] : bb1[nt & 3];
            f32x4 v = {b, b, b, b};
            acc[nt] = v;
        }
        step_gemm(acc, wr, Blds[wv], wpd, A[R], lane, l15, lg);

        float hnv[2][4];
#pragma unroll
        for (int half = 0; half < 2; ++half) {
#pragma unroll
            for (int r = 0; r < 4; ++r) {
                float iv = acc[0 + half][r];
                float fv = acc[2 + half][r];
                float gv = acc[4 + half][r];
                float ov = acc[6 + half][r];
                float cn = sigm(fv) * c_st[half][r] + sigm(iv) * tanh_f(gv);
                c_st[half][r] = cn;
                float hn = sigm(ov) * tanh_f(cn);
                hnv[half][r] = hn;
                A[Wb][lg * 4 + r][wv * 32 + half * 16 + l15] = (_Float16)hn;
            }
        }
#pragma unroll
        for (int r = 0; r < 4; ++r) {
            float pv = hnv[0][r] * fcw0 + hnv[1][r] * fcw1;
            pv += __shfl_xor(pv, 1);
            pv += __shfl_xor(pv, 2);
            pv += __shfl_xor(pv, 4);
            pv += __shfl_xor(pv, 8);
            if (l15 == 0) partial[wv][lg * 4 + r] = pv;
        }
        __syncthreads();
        if (tid < 16) {
            float pr = fcbv;
#pragma unroll
            for (int w = 0; w < 8; ++w) pr += partial[w][tid];
            out[(size_t)(b0 + tid) * 96 + s] = pr;      // direct store (no outstage)
            A[Wb][tid][256] = (_Float16)pr;             // feed back as next x
        }
        __syncthreads();
    }
}

// ---------- launch ----------

extern "C" void kernel_launch(void* const* d_in, const int* in_sizes, int n_in,
                              void* d_out, int out_size, void* d_ws, size_t ws_size,
                              hipStream_t stream) {
    const float* inputs  = (const float*)d_in[0];
    const float* enc_Wih = (const float*)d_in[1];
    const float* enc_Whh = (const float*)d_in[2];
    const float* enc_bih = (const float*)d_in[3];
    const float* enc_bhh = (const float*)d_in[4];
    const float* dec_Wih = (const float*)d_in[5];
    const float* dec_Whh = (const float*)d_in[6];
    const float* dec_bih = (const float*)d_in[7];
    const float* dec_bhh = (const float*)d_in[8];
    const float* fc_W    = (const float*)d_in[9];
    const float* fc_b    = (const float*)d_in[10];

    char* ws = (char*)d_ws;
    _Float16* xf16 = (_Float16*)(ws);                       // 2,752,512 B
    _Float16* WpE  = (_Float16*)(ws + 2752512);             //   589,824 B
    _Float16* WpD  = (_Float16*)(ws + 2752512 + 589824);    //   589,824 B

    k_convert_x<<<dim3(5376), dim3(256), 0, stream>>>(inputs, xf16);
    k_pack_w<<<dim3(1152), dim3(256), 0, stream>>>(enc_Whh, enc_Wih, 8, WpE);
    k_pack_w<<<dim3(1152), dim3(256), 0, stream>>>(dec_Whh, dec_Wih, 1, WpD);

    lstm_seq2seq<<<dim3(64), dim3(512), 0, stream>>>(
        xf16, WpE, WpD, enc_bih, enc_bhh, dec_bih, dec_bhh, fc_W, fc_b, (float*)d_out);
}

// Round 3
// 1122.848 us; speedup vs baseline: 2.0906x; 1.0803x over previous
//
#include <hip/hip_runtime.h>

// Seq2Seq LSTM (B=1024, T_IN=168, F_IN=8, H=256, T_OUT=96) on gfx950.
// Round 3: near-fully weight-resident, latency-trimmed.
//   kt0-4  : VGPR-resident (40 f16x8 = 160 regs/wave)
//   kt5    : streamed from L2 (64 KB/CU/step, one batch, hidden under reg MFMAs)
//   kt6-7  : LDS-resident (128 KB)
//   kt8(x) : LDS-resident COMPRESSED (only B-lanes 0-15 are nonzero -> 16 KB),
//            broadcast-read + lane-mask multiply
//   A tile : single-buffer 16x256 f16, XOR bank-swizzle, 2 barriers/step
//   bias   : permanent VGPRs, folded into activation (acc init = 0)
//   x      : tiny xs[16][8] staging row; x[t+1] prefetched into a reg
// 64 blocks x 512 threads (8 waves; wave wv owns gate-cols wv*32..+32).

typedef _Float16 f16x8 __attribute__((ext_vector_type(8)));
typedef float f32x4 __attribute__((ext_vector_type(4)));

#define WPW  36864          // packed f16 per wave per weight set: 9kt*8nt*64lane*8
#define NSTEPS_ENC 168
#define NSTEPS_DEC 96

__device__ __forceinline__ float sigm(float x) {
    float e = __builtin_amdgcn_exp2f(-1.4426950408889634f * x);
    return __builtin_amdgcn_rcpf(1.0f + e);
}
__device__ __forceinline__ float tanh_f(float x) {
    float e = __builtin_amdgcn_exp2f(-2.8853900817779268f * x);
    return 2.0f * __builtin_amdgcn_rcpf(1.0f + e) - 1.0f;
}

__device__ __forceinline__ void mfma8(f32x4 acc[8], f16x8 a, const f16x8 b[8]) {
#pragma unroll
    for (int nt = 0; nt < 8; ++nt)
        acc[nt] = __builtin_amdgcn_mfma_f32_16x16x32_f16(a, b[nt], acc[nt], 0, 0, 0);
}

// full 16x288 gate GEMM for one step (acc starts at 0, bias folded later)
__device__ __forceinline__ void gemm_all(f32x4 acc[8],
                                         const f16x8 wr[5][8],
                                         const f16x8 (*Bw)[64],   // [16][64] LDS kt6,7
                                         const f16x8 (*K8w)[16],  // [8][16]  LDS kt8 packed
                                         const _Float16* __restrict__ wp,
                                         const char* ab, int abase,
                                         const _Float16* xsrow,
                                         int lane, int l15, int lg) {
    // streamed kt5 (constant address every step; L2-resident)
    f16x8 s5[8];
#pragma unroll
    for (int nt = 0; nt < 8; ++nt)
        s5[nt] = *(const f16x8*)(wp + ((5 * 8 + nt) * 64 + lane) * 8);

    // register-resident kt0..4
#pragma unroll
    for (int kt = 0; kt < 5; ++kt) {
        f16x8 a = *(const f16x8*)(ab + abase + kt * 64);
        mfma8(acc, a, wr[kt]);
    }
    // streamed kt5
    {
        f16x8 a = *(const f16x8*)(ab + abase + 5 * 64);
        mfma8(acc, a, s5);
    }
    // LDS-resident kt6..7
#pragma unroll
    for (int kt = 6; kt < 8; ++kt) {
        f16x8 a = *(const f16x8*)(ab + abase + kt * 64);
#pragma unroll
        for (int nt = 0; nt < 8; ++nt)
            acc[nt] = __builtin_amdgcn_mfma_f32_16x16x32_f16(a, Bw[(kt - 6) * 8 + nt][lane], acc[nt], 0, 0, 0);
    }
    // kt8: x projection. B nonzero only for lanes 0-15 (lg==0); packed 16 lanes in LDS.
    {
        f16x8 a = *(const f16x8*)xsrow;             // lanes lg>0 read junk * 0-weight
        _Float16 m = (_Float16)(lg == 0 ? 1.0f : 0.0f);
#pragma unroll
        for (int nt = 0; nt < 8; ++nt) {
            f16x8 b = K8w[nt][l15] * m;
            acc[nt] = __builtin_amdgcn_mfma_f32_16x16x32_f16(a, b, acc[nt], 0, 0, 0);
        }
    }
}

// ---------- setup kernels ----------

__global__ void k_convert_x(const float* __restrict__ in, _Float16* __restrict__ xf16) {
    int idx = blockIdx.x * 256 + threadIdx.x;     // (t*1024 + b)*8 + f
    if (idx >= 168 * 1024 * 8) return;
    int f = idx & 7;
    int b = (idx >> 3) & 1023;
    int t = idx >> 13;
    xf16[idx] = (_Float16)in[(b * 168 + t) * 8 + f];
}

__global__ void k_pack_w(const float* __restrict__ Whh, const float* __restrict__ Wih,
                         int IN, _Float16* __restrict__ Wp) {
    int idx = blockIdx.x * 256 + threadIdx.x;
    if (idx >= 294912) return;
    int j    = idx & 7;
    int lane = (idx >> 3) & 63;
    int nt   = (idx >> 9) & 7;
    int kt   = (idx >> 12) % 9;
    int wv   = idx / 36864;
    int n = (nt >> 1) * 256 + wv * 32 + (nt & 1) * 16 + (lane & 15);
    int k = kt * 32 + (lane >> 4) * 8 + j;
    float v = 0.0f;
    if (k < 256)            v = Whh[n * 256 + k];
    else if (k - 256 < IN)  v = Wih[n * IN + (k - 256)];
    Wp[idx] = (_Float16)v;
}

// ---------- main persistent kernel ----------

__global__ __launch_bounds__(512, 2) void lstm_seq2seq(
    const _Float16* __restrict__ xf16,
    const _Float16* __restrict__ WpE,
    const _Float16* __restrict__ WpD,
    const float* __restrict__ bihE, const float* __restrict__ bhhE,
    const float* __restrict__ bihD, const float* __restrict__ bhhD,
    const float* __restrict__ fcW,
    const float* __restrict__ fcb,
    float* __restrict__ out) {

    __shared__ f16x8 Blds[8][16][64];     // 128 KB  kt6,7 per wave
    __shared__ f16x8 K8[8][8][16];        //  16 KB  kt8 packed (lanes 0-15 only)
    __shared__ _Float16 Abuf[16 * 256];   //   8 KB  h tile, XOR-swizzled
    __shared__ _Float16 xs[16][8];        //  256 B  x staging (current step)
    __shared__ float partial[8][16];      //  512 B  decoder fc partials

    const int tid  = threadIdx.x;
    const int lane = tid & 63;
    const int wv   = tid >> 6;
    const int l15  = lane & 15;
    const int lg   = lane >> 4;
    const int b0   = blockIdx.x * 16;

    const char* ab = (const char*)Abuf;
    const int abase = l15 * 512 + ((lg * 16) ^ ((l15 & 3) << 4));   // swizzled A read base

    // zero Abuf (h0 = 0; zeros are swizzle-invariant)
    for (int i = tid; i < 16 * 256; i += 512) Abuf[i] = (_Float16)0.0f;

    const _Float16* wpe = WpE + wv * WPW;
    const _Float16* wpd = WpD + wv * WPW;

    // encoder weights: regs kt0-4, LDS kt6-7, packed kt8
    f16x8 wr[5][8];
#pragma unroll
    for (int kt = 0; kt < 5; ++kt)
#pragma unroll
        for (int nt = 0; nt < 8; ++nt)
            wr[kt][nt] = *(const f16x8*)(wpe + ((kt * 8 + nt) * 64 + lane) * 8);
#pragma unroll
    for (int kt = 6; kt < 8; ++kt)
#pragma unroll
        for (int nt = 0; nt < 8; ++nt)
            Blds[wv][(kt - 6) * 8 + nt][lane] = *(const f16x8*)(wpe + ((kt * 8 + nt) * 64 + lane) * 8);
    if (lane < 16) {
#pragma unroll
        for (int nt = 0; nt < 8; ++nt)
            K8[wv][nt][lane] = *(const f16x8*)(wpe + ((8 * 8 + nt) * 64 + lane) * 8);
    }
    // encoder bias, permanent regs
    float bia[8];
#pragma unroll
    for (int nt = 0; nt < 8; ++nt) {
        int n = (nt >> 1) * 256 + wv * 32 + (nt & 1) * 16 + l15;
        bia[nt] = bihE[n] + bhhE[n];
    }

    float c_st[2][4] = {{0.f,0.f,0.f,0.f},{0.f,0.f,0.f,0.f}};

    __syncthreads();
    if (tid < 128) {                       // x_0 into xs
        int m = tid >> 3, f = tid & 7;
        xs[m][f] = xf16[(size_t)(b0 + m) * 8 + f];
    }
    __syncthreads();

    // ===================== encoder: 168 steps =====================
#pragma unroll 1
    for (int t = 0; t < NSTEPS_ENC; ++t) {
        f32x4 acc[8];
#pragma unroll
        for (int nt = 0; nt < 8; ++nt) { f32x4 z = {0.f,0.f,0.f,0.f}; acc[nt] = z; }

        // prefetch next x into a register (off critical path)
        _Float16 xh = (_Float16)0.0f;
        if (t < NSTEPS_ENC - 1 && tid < 128)
            xh = xf16[(size_t)((t + 1) * 1024 + b0 + (tid >> 3)) * 8 + (tid & 7)];

        gemm_all(acc, wr, Blds[wv], K8[wv], wpe, ab, abase, &xs[l15][0], lane, l15, lg);

        float hnv[2][4];
#pragma unroll
        for (int half = 0; half < 2; ++half) {
#pragma unroll
            for (int r = 0; r < 4; ++r) {
                float iv = acc[0 + half][r] + bia[0 + half];
                float fv = acc[2 + half][r] + bia[2 + half];
                float gv = acc[4 + half][r] + bia[4 + half];
                float ov = acc[6 + half][r] + bia[6 + half];
                float cn = sigm(fv) * c_st[half][r] + sigm(iv) * tanh_f(gv);
                c_st[half][r] = cn;
                hnv[half][r] = sigm(ov) * tanh_f(cn);
            }
        }
        __syncthreads();                    // all GEMM reads of Abuf/xs complete
        // write h (swizzled) + next x
#pragma unroll
        for (int half = 0; half < 2; ++half) {
#pragma unroll
            for (int r = 0; r < 4; ++r) {
                int row = lg * 4 + r;
                int colb = (wv * 32 + half * 16 + l15) * 2;
                *(_Float16*)((char*)Abuf + row * 512 + (colb ^ ((r & 3) << 4))) = (_Float16)hnv[half][r];
            }
        }
        if (t < NSTEPS_ENC - 1) {
            if (tid < 128) xs[tid >> 3][tid & 7] = xh;
        } else {
            if (tid < 16) {                 // decoder x0 = x[167][0]; zero other feats
#pragma unroll
                for (int f = 1; f < 8; ++f) xs[tid][f] = (_Float16)0.0f;
            }
        }
        __syncthreads();
    }

    // ---------- phase switch: decoder weights ----------
#pragma unroll
    for (int kt = 0; kt < 5; ++kt)
#pragma unroll
        for (int nt = 0; nt < 8; ++nt)
            wr[kt][nt] = *(const f16x8*)(wpd + ((kt * 8 + nt) * 64 + lane) * 8);
#pragma unroll
    for (int kt = 6; kt < 8; ++kt)
#pragma unroll
        for (int nt = 0; nt < 8; ++nt)
            Blds[wv][(kt - 6) * 8 + nt][lane] = *(const f16x8*)(wpd + ((kt * 8 + nt) * 64 + lane) * 8);
    if (lane < 16) {
#pragma unroll
        for (int nt = 0; nt < 8; ++nt)
            K8[wv][nt][lane] = *(const f16x8*)(wpd + ((8 * 8 + nt) * 64 + lane) * 8);
    }
#pragma unroll
    for (int nt = 0; nt < 8; ++nt) {
        int n = (nt >> 1) * 256 + wv * 32 + (nt & 1) * 16 + l15;
        bia[nt] = bihD[n] + bhhD[n];
    }
    float fcw0 = fcW[wv * 32 + l15];
    float fcw1 = fcW[wv * 32 + 16 + l15];
    float fcbv = fcb[0];
    __syncthreads();

    // ===================== decoder: 96 steps (autoregressive) =====================
#pragma unroll 1
    for (int s = 0; s < NSTEPS_DEC; ++s) {
        f32x4 acc[8];
#pragma unroll
        for (int nt = 0; nt < 8; ++nt) { f32x4 z = {0.f,0.f,0.f,0.f}; acc[nt] = z; }

        gemm_all(acc, wr, Blds[wv], K8[wv], wpd, ab, abase, &xs[l15][0], lane, l15, lg);

        float hnv[2][4];
#pragma unroll
        for (int half = 0; half < 2; ++half) {
#pragma unroll
            for (int r = 0; r < 4; ++r) {
                float iv = acc[0 + half][r] + bia[0 + half];
                float fv = acc[2 + half][r] + bia[2 + half];
                float gv = acc[4 + half][r] + bia[4 + half];
                float ov = acc[6 + half][r] + bia[6 + half];
                float cn = sigm(fv) * c_st[half][r] + sigm(iv) * tanh_f(gv);
                c_st[half][r] = cn;
                hnv[half][r] = sigm(ov) * tanh_f(cn);
            }
        }
        // fc partial: reduce this wave's 32 hidden cols (pre-barrier)
#pragma unroll
        for (int r = 0; r < 4; ++r) {
            float pv = hnv[0][r] * fcw0 + hnv[1][r] * fcw1;
            pv += __shfl_xor(pv, 1);
            pv += __shfl_xor(pv, 2);
            pv += __shfl_xor(pv, 4);
            pv += __shfl_xor(pv, 8);
            if (l15 == 0) partial[wv][lg * 4 + r] = pv;
        }
        __syncthreads();                    // GEMM reads done + partials visible
        // h writes (parallel with pred computation by tid<16)
#pragma unroll
        for (int half = 0; half < 2; ++half) {
#pragma unroll
            for (int r = 0; r < 4; ++r) {
                int row = lg * 4 + r;
                int colb = (wv * 32 + half * 16 + l15) * 2;
                *(_Float16*)((char*)Abuf + row * 512 + (colb ^ ((r & 3) << 4))) = (_Float16)hnv[half][r];
            }
        }
        if (tid < 16) {
            float pr = fcbv;
#pragma unroll
            for (int w = 0; w < 8; ++w) pr += partial[w][tid];
            out[(size_t)(b0 + tid) * 96 + s] = pr;
            xs[tid][0] = (_Float16)pr;      // autoregressive feedback
        }
        __syncthreads();
    }
}

// ---------- launch ----------

extern "C" void kernel_launch(void* const* d_in, const int* in_sizes, int n_in,
                              void* d_out, int out_size, void* d_ws, size_t ws_size,
                              hipStream_t stream) {
    const float* inputs  = (const float*)d_in[0];
    const float* enc_Wih = (const float*)d_in[1];
    const float* enc_Whh = (const float*)d_in[2];
    const float* enc_bih = (const float*)d_in[3];
    const float* enc_bhh = (const float*)d_in[4];
    const float* dec_Wih = (const float*)d_in[5];
    const float* dec_Whh = (const float*)d_in[6];
    const float* dec_bih = (const float*)d_in[7];
    const float* dec_bhh = (const float*)d_in[8];
    const float* fc_W    = (const float*)d_in[9];
    const float* fc_b    = (const float*)d_in[10];

    char* ws = (char*)d_ws;
    _Float16* xf16 = (_Float16*)(ws);                       // 2,752,512 B
    _Float16* WpE  = (_Float16*)(ws + 2752512);             //   589,824 B
    _Float16* WpD  = (_Float16*)(ws + 2752512 + 589824);    //   589,824 B

    k_convert_x<<<dim3(5376), dim3(256), 0, stream>>>(inputs, xf16);
    k_pack_w<<<dim3(1152), dim3(256), 0, stream>>>(enc_Whh, enc_Wih, 8, WpE);
    k_pack_w<<<dim3(1152), dim3(256), 0, stream>>>(dec_Whh, dec_Wih, 1, WpD);

    lstm_seq2seq<<<dim3(64), dim3(512), 0, stream>>>(
        xf16, WpE, WpD, enc_bih, enc_bhh, dec_bih, dec_bhh, fc_W, fc_b, (float*)d_out);
}